// Round 9
// baseline (191.598 us; speedup 1.0000x reference)
//
#include <hip/hip_runtime.h>
#include <math.h>

#pragma clang fp contract(off)

#define VV 5
#define BB 2
#define CC 32
#define HH 128
#define WW 128
#define DD 32
#define GG 8
#define HWW (HH*WW)

// ---------------------------------------------------------------------------
// Kernel 1: numpy(OpenBLAS)-faithful projection setup.
//   make_proj einsum: FMA-contracted k-chain (numpy einsum C loops compiled
//   with gcc -ffp-contract=fast on x86-64).
//   inv: sgesv (getf2 FMA rank-1 + laswp + OpenBLAS trsm w/ inverted diag).
//   src@inv: sgemm FMA k-chain.
// ---------------------------------------------------------------------------
__global__ void proj_kernel(const float* __restrict__ pm, float* __restrict__ wproj) {
#pragma clang fp contract(off)
    int tid = threadIdx.x;
    if (tid >= BB * (VV - 1)) return;
    int b = tid / (VV - 1);
    int v = tid % (VV - 1) + 1;

    float refP[4][4], srcP[4][4];
    for (int which = 0; which < 2; which++) {
        int view = (which == 0) ? 0 : v;
        const float* base = pm + (size_t)(b * VV + view) * 2 * 16;
        const float* ext  = base;       // p[:,0]
        const float* intr = base + 16;  // p[:,1]
        float (*M)[4] = (which == 0) ? refP : srcP;
        for (int r = 0; r < 3; r++)
            for (int c = 0; c < 4; c++) {
                float s = 0.f;
                for (int k = 0; k < 3; k++)
                    s = fmaf(intr[r * 4 + k], ext[k * 4 + c], s);   // einsum FMA chain
                M[r][c] = s;
            }
        for (int c = 0; c < 4; c++) M[3][c] = ext[12 + c];
    }

    // ---- getf2: first-max pivot, reciprocal scale, rank-1 update (FMA)
    float A[4][4];
    for (int r = 0; r < 4; r++)
        for (int c = 0; c < 4; c++) A[r][c] = refP[r][c];
    int ipiv[4];
    for (int j = 0; j < 4; j++) {
        int p = j; float amax = fabsf(A[j][j]);
        for (int i = j + 1; i < 4; i++) {
            float t = fabsf(A[i][j]);
            if (t > amax) { amax = t; p = i; }   // first max wins
        }
        ipiv[j] = p;
        if (p != j)
            for (int c = 0; c < 4; c++) { float t = A[j][c]; A[j][c] = A[p][c]; A[p][c] = t; }
        float rcp = 1.0f / A[j][j];
        for (int i = j + 1; i < 4; i++) A[i][j] = A[i][j] * rcp;
        for (int i = j + 1; i < 4; i++)
            for (int k = j + 1; k < 4; k++)
                A[i][k] = fmaf(-A[i][j], A[j][k], A[i][k]);
    }

    // ---- getrs(I): laswp, trsm L(unit) fwd, trsm U(non-unit, inv-diag) bwd
    float Bm[4][4];
    for (int r = 0; r < 4; r++)
        for (int c = 0; c < 4; c++) Bm[r][c] = (r == c) ? 1.f : 0.f;
    for (int j = 0; j < 4; j++) {
        int p = ipiv[j];
        if (p != j)
            for (int c = 0; c < 4; c++) { float t = Bm[j][c]; Bm[j][c] = Bm[p][c]; Bm[p][c] = t; }
    }
    float invd[4];
    for (int k = 0; k < 4; k++) invd[k] = 1.0f / A[k][k];
    for (int c = 0; c < 4; c++) {
        for (int k = 0; k < 4; k++)
            for (int i = k + 1; i < 4; i++)
                Bm[i][c] = fmaf(-A[i][k], Bm[k][c], Bm[i][c]);
        for (int k = 3; k >= 0; k--) {
            Bm[k][c] = Bm[k][c] * invd[k];
            for (int i = 0; i < k; i++)
                Bm[i][c] = fmaf(-A[i][k], Bm[k][c], Bm[i][c]);
        }
    }

    // ---- P = srcP @ invRef (sgemm beta=0): FMA chain from 0, k ascending
    float P[3][4];
    for (int r = 0; r < 3; r++)
        for (int c = 0; c < 4; c++) {
            float s = 0.f;
            for (int k = 0; k < 4; k++)
                s = fmaf(srcP[r][k], Bm[k][c], s);
            P[r][c] = s;
        }
    float* o = wproj + (b * (VV - 1) + (v - 1)) * 12;
    for (int r = 0; r < 3; r++)
        for (int c = 0; c < 3; c++) o[r * 3 + c] = P[r][c];
    for (int r = 0; r < 3; r++) o[9 + r] = P[r][3];
}

// ---------------------------------------------------------------------------
// Kernel 2: transpose features [VB,C,H,W] -> channel-last [VB,H,W,C]
// ---------------------------------------------------------------------------
__global__ __launch_bounds__(256) void transpose_kernel(const float* __restrict__ fea,
                                                        float* __restrict__ featT) {
    __shared__ float tile[64][33];
    int t = threadIdx.x;
    int vb = blockIdx.x >> 8;
    int base = (blockIdx.x & 255) * 64;
#pragma unroll
    for (int k = 0; k < 8; k++) {
        int idx = k * 256 + t;
        int c = idx >> 6;
        int pl = idx & 63;
        tile[pl][c] = fea[((size_t)vb * CC + c) * HWW + base + pl];
    }
    __syncthreads();
#pragma unroll
    for (int k = 0; k < 8; k++) {
        int idx = k * 256 + t;
        int pl = idx >> 5;
        int c = idx & 31;
        featT[((size_t)vb * HWW + base + pl) * CC + c] = tile[pl][c];
    }
}

// ---------------------------------------------------------------------------
// Kernel 3: numpy-f32-faithful fused pipeline.
//   einsum chains (rot_xyz, final logit) now FMA-contracted; ufunc array ops
//   (mul, add, div) stay separately rounded. Plain first-occurrence argmax.
// ---------------------------------------------------------------------------
__global__ __launch_bounds__(256) void main_kernel(const float* __restrict__ featT,
                                                   const float* __restrict__ wproj,
                                                   const float* __restrict__ depth_hypo,
                                                   const float* __restrict__ reg_w,
                                                   float* __restrict__ out) {
#pragma clang fp contract(off)
    __shared__ float s_ref[8][32];
    __shared__ float s_proj[4][12];
    __shared__ float s_regw[8];

    int t = threadIdx.x;
    int d = t & 31, pl = t >> 5;
    int base = t & 32;                    // wave-half base lane for shfl scans
    int pixbase = blockIdx.x * 8;
    int b = pixbase / HWW;
    int hwb = pixbase - b * HWW;

    s_ref[pl][d] = featT[((size_t)(b * HWW + hwb + pl)) * CC + d];
    if (t < 48) s_proj[t / 12][t % 12] = wproj[b * (VV - 1) * 12 + t];
    if (t < 8) s_regw[t] = reg_w[t];
    __syncthreads();

    int hw = hwb + pl;
    int y = hw >> 7, x = hw & (WW - 1);
    float fx = (float)x, fy = (float)y;
    float dep = depth_hypo[(size_t)(b * DD + d) * HWW + hw];

    float4 ref4[8];
#pragma unroll
    for (int g = 0; g < 8; g++) ref4[g] = *(const float4*)&s_ref[pl][g * 4];

    float accs[8];
#pragma unroll
    for (int g = 0; g < 8; g++) accs[g] = 0.f;
    float cws = 1e-8f;

    for (int vi = 0; vi < 4; vi++) {
        const float* pr = s_proj[vi];
        // einsum 'bij,jn->bin' FMA j-chain: fma(r1,y, r0*x) then +r2 (the *1
        // term fuses to a plain add). Then ufunc mul/add: *dep, +trans.
        float rx = fmaf(pr[1], fy, pr[0] * fx) + pr[2];
        float ry = fmaf(pr[4], fy, pr[3] * fx) + pr[5];
        float rz = fmaf(pr[7], fy, pr[6] * fx) + pr[8];
        float X = rx * dep + pr[9];
        float Y = ry * dep + pr[10];
        float Z = rz * dep + pr[11];
        if (Z == 0.f) Z = 1e-9f;
        float px = X / Z, py = Y / Z;

        float x0f = floorf(px), y0f = floorf(py);
        float x1f = x0f + 1.0f, y1f = y0f + 1.0f;
        float wx1 = px - x0f, wx0 = 1.0f - wx1;
        float wy1 = py - y0f, wy0 = 1.0f - wy1;
        bool vx0 = (x0f >= 0.f) && (x0f <= (float)(WW - 1));
        bool vx1 = (x1f >= 0.f) && (x1f <= (float)(WW - 1));
        bool vy0 = (y0f >= 0.f) && (y0f <= (float)(HH - 1));
        bool vy1 = (y1f >= 0.f) && (y1f <= (float)(HH - 1));

        int xc0 = (int)fminf(fmaxf(x0f, 0.f), (float)(WW - 1));
        int xc1 = (int)fminf(fmaxf(x1f, 0.f), (float)(WW - 1));
        int yc0 = (int)fminf(fmaxf(y0f, 0.f), (float)(HH - 1));
        int yc1 = (int)fminf(fmaxf(y1f, 0.f), (float)(HH - 1));

        float w00 = (wx0 * wy0) * ((vx0 && vy0) ? 1.f : 0.f);
        float w10 = (wx1 * wy0) * ((vx1 && vy0) ? 1.f : 0.f);
        float w01 = (wx0 * wy1) * ((vx0 && vy1) ? 1.f : 0.f);
        float w11 = (wx1 * wy1) * ((vx1 && vy1) ? 1.f : 0.f);

        const float* srcB = featT + (size_t)((vi + 1) * BB + b) * HWW * CC;
        const float4* p00 = (const float4*)(srcB + ((size_t)yc0 * WW + xc0) * CC);
        const float4* p10 = (const float4*)(srcB + ((size_t)yc0 * WW + xc1) * CC);
        const float4* p01 = (const float4*)(srcB + ((size_t)yc1 * WW + xc0) * CC);
        const float4* p11 = (const float4*)(srcB + ((size_t)yc1 * WW + xc1) * CC);

        // warped = ((t00*w00 + t10*w10) + t01*w01) + t11*w11 (ufunc array adds,
        // separately rounded); prod = warped*ref; mean over 4 sequential, /4 exact.
        float cf[8];
        float s = 0.f;
#pragma unroll
        for (int g = 0; g < 8; g++) {
            float4 f00 = p00[g], f10 = p10[g], f01 = p01[g], f11 = p11[g];
            float wrp[4];
            {
                float a;
                a = f00.x * w00; a = a + f10.x * w10; a = a + f01.x * w01; a = a + f11.x * w11; wrp[0] = a;
                a = f00.y * w00; a = a + f10.y * w10; a = a + f01.y * w01; a = a + f11.y * w11; wrp[1] = a;
                a = f00.z * w00; a = a + f10.z * w10; a = a + f01.z * w01; a = a + f11.z * w11; wrp[2] = a;
                a = f00.w * w00; a = a + f10.w * w10; a = a + f01.w * w01; a = a + f11.w * w11; wrp[3] = a;
            }
            float pr0 = wrp[0] * ref4[g].x;
            float pr1 = wrp[1] * ref4[g].y;
            float pr2 = wrp[2] * ref4[g].z;
            float pr3 = wrp[3] * ref4[g].w;
            float gs = pr0;
            gs = gs + pr1; gs = gs + pr2; gs = gs + pr3;
            gs = gs * 0.25f;
            cf[g] = gs;
            s = s + gs;                      // sum over g: strided axis, sequential
        }

        // softmax over d: max order-free; denominator sequential in d-order
        float m = s;
#pragma unroll
        for (int msk = 1; msk < 32; msk <<= 1) m = fmaxf(m, __shfl_xor(m, msk, 64));
        float e = expf(s - m);
        float sum = 0.f;
        for (int i = 0; i < 32; i++) {
            float vv = __shfl(e, base + i, 64);
            sum = sum + vv;
        }
        float cw = (e / sum) * 0.17677669529663687f;   // * f32(1/sqrt(32))

        cws = cws + cw;
#pragma unroll
        for (int g = 0; g < 8; g++) {
            float tterm = cw * cf[g];
            accs[g] = accs[g] + tterm;
        }
    }

    // cor_feats / cws elementwise (ufunc), then einsum over g: FMA chain
    float logit = 0.f;
#pragma unroll
    for (int g = 0; g < 8; g++) {
        float cfn = accs[g] / cws;
        logit = fmaf(s_regw[g], cfn, logit);
    }

    // final softmax over d
    float m2 = logit;
#pragma unroll
    for (int msk = 1; msk < 32; msk <<= 1) m2 = fmaxf(m2, __shfl_xor(m2, msk, 64));
    float e2 = expf(logit - m2);
    float s2 = 0.f;
    for (int i = 0; i < 32; i++) {
        float vv = __shfl(e2, base + i, 64);
        s2 = s2 + vv;
    }
    float attn = e2 / s2;
    out[(size_t)BB * HWW + (size_t)(b * DD + d) * HWW + hw] = attn;

    // np.argmax: first occurrence of the bitwise max
    float a1 = attn;
#pragma unroll
    for (int msk = 1; msk < 32; msk <<= 1) a1 = fmaxf(a1, __shfl_xor(a1, msk, 64));
    int idx1 = (attn == a1) ? d : 1000;
#pragma unroll
    for (int msk = 1; msk < 32; msk <<= 1) {
        int oi = __shfl_xor(idx1, msk, 64);
        idx1 = (oi < idx1) ? oi : idx1;
    }
    float dep1 = __shfl(dep, base + idx1, 64);
    if (d == 0) out[b * HWW + hw] = dep1;
}

// ---------------------------------------------------------------------------
extern "C" void kernel_launch(void* const* d_in, const int* in_sizes, int n_in,
                              void* d_out, int out_size, void* d_ws, size_t ws_size,
                              hipStream_t stream) {
    const float* features   = (const float*)d_in[0];   // [V,B,C,H,W]
    const float* pm         = (const float*)d_in[1];   // [B,V,2,4,4]
    const float* depth_hypo = (const float*)d_in[2];   // [B,D,H,W]
    const float* reg_w      = (const float*)d_in[3];   // [G]
    float* out = (float*)d_out;                        // depth [B,H,W] ++ attn [B,D,H,W]

    float* wproj = (float*)d_ws;                       // 96 floats
    float* featT = (float*)((char*)d_ws + 4096);       // [VB,H,W,C] = 21 MB

    proj_kernel<<<1, 64, 0, stream>>>(pm, wproj);
    transpose_kernel<<<VV * BB * (HWW / 64), 256, 0, stream>>>(features, featT);
    main_kernel<<<BB * HWW / 8, 256, 0, stream>>>(featT, wproj, depth_hypo, reg_w, out);
}

// Round 10
// 154.547 us; speedup vs baseline: 1.2397x; 1.2397x over previous
//
#include <hip/hip_runtime.h>
#include <math.h>

#pragma clang fp contract(off)

#define VV 5
#define BB 2
#define CC 32
#define HH 128
#define WW 128
#define DD 32
#define GG 8
#define HWW (HH*WW)
#define TRBLOCKS (VV*BB*(HWW/64))   // 2560 transpose blocks

// ---------------------------------------------------------------------------
// Kernel 1 (fused): transpose features [VB,C,H,W] -> [VB,H,W,C]  +  proj setup.
// Block TRBLOCKS does the projection math (bit-identical to the r9 passing
// version); all other blocks transpose. Saves one kernel launch.
// ---------------------------------------------------------------------------
__global__ __launch_bounds__(256) void prep_kernel(const float* __restrict__ fea,
                                                   float* __restrict__ featT,
                                                   const float* __restrict__ pm,
                                                   float* __restrict__ wproj) {
#pragma clang fp contract(off)
    int t = threadIdx.x;
    if (blockIdx.x == TRBLOCKS) {
        // ---------------- projection (numpy/OpenBLAS-faithful, FROZEN r9 bits)
        int tid = t;
        if (tid >= BB * (VV - 1)) return;
        int b = tid / (VV - 1);
        int v = tid % (VV - 1) + 1;

        float refP[4][4], srcP[4][4];
        for (int which = 0; which < 2; which++) {
            int view = (which == 0) ? 0 : v;
            const float* base = pm + (size_t)(b * VV + view) * 2 * 16;
            const float* ext  = base;
            const float* intr = base + 16;
            float (*M)[4] = (which == 0) ? refP : srcP;
            for (int r = 0; r < 3; r++)
                for (int c = 0; c < 4; c++) {
                    float s = 0.f;
                    for (int k = 0; k < 3; k++)
                        s = fmaf(intr[r * 4 + k], ext[k * 4 + c], s);  // einsum FMA chain
                    M[r][c] = s;
                }
            for (int c = 0; c < 4; c++) M[3][c] = ext[12 + c];
        }

        float A[4][4];
        for (int r = 0; r < 4; r++)
            for (int c = 0; c < 4; c++) A[r][c] = refP[r][c];
        int ipiv[4];
        for (int j = 0; j < 4; j++) {
            int p = j; float amax = fabsf(A[j][j]);
            for (int i = j + 1; i < 4; i++) {
                float tt = fabsf(A[i][j]);
                if (tt > amax) { amax = tt; p = i; }
            }
            ipiv[j] = p;
            if (p != j)
                for (int c = 0; c < 4; c++) { float tt = A[j][c]; A[j][c] = A[p][c]; A[p][c] = tt; }
            float rcp = 1.0f / A[j][j];
            for (int i = j + 1; i < 4; i++) A[i][j] = A[i][j] * rcp;
            for (int i = j + 1; i < 4; i++)
                for (int k = j + 1; k < 4; k++)
                    A[i][k] = fmaf(-A[i][j], A[j][k], A[i][k]);
        }

        float Bm[4][4];
        for (int r = 0; r < 4; r++)
            for (int c = 0; c < 4; c++) Bm[r][c] = (r == c) ? 1.f : 0.f;
        for (int j = 0; j < 4; j++) {
            int p = ipiv[j];
            if (p != j)
                for (int c = 0; c < 4; c++) { float tt = Bm[j][c]; Bm[j][c] = Bm[p][c]; Bm[p][c] = tt; }
        }
        float invd[4];
        for (int k = 0; k < 4; k++) invd[k] = 1.0f / A[k][k];
        for (int c = 0; c < 4; c++) {
            for (int k = 0; k < 4; k++)
                for (int i = k + 1; i < 4; i++)
                    Bm[i][c] = fmaf(-A[i][k], Bm[k][c], Bm[i][c]);
            for (int k = 3; k >= 0; k--) {
                Bm[k][c] = Bm[k][c] * invd[k];
                for (int i = 0; i < k; i++)
                    Bm[i][c] = fmaf(-A[i][k], Bm[k][c], Bm[i][c]);
            }
        }

        float P[3][4];
        for (int r = 0; r < 3; r++)
            for (int c = 0; c < 4; c++) {
                float s = 0.f;
                for (int k = 0; k < 4; k++)
                    s = fmaf(srcP[r][k], Bm[k][c], s);
                P[r][c] = s;
            }
        float* o = wproj + (b * (VV - 1) + (v - 1)) * 12;
        for (int r = 0; r < 3; r++)
            for (int c = 0; c < 3; c++) o[r * 3 + c] = P[r][c];
        for (int r = 0; r < 3; r++) o[9 + r] = P[r][3];
        return;
    }

    // ---------------- transpose tile (bit-exact copy)
    __shared__ float tile[64][33];
    int vb = blockIdx.x >> 8;
    int base = (blockIdx.x & 255) * 64;
#pragma unroll
    for (int k = 0; k < 8; k++) {
        int idx = k * 256 + t;
        int c = idx >> 6;
        int pl = idx & 63;
        tile[pl][c] = fea[((size_t)vb * CC + c) * HWW + base + pl];
    }
    __syncthreads();
#pragma unroll
    for (int k = 0; k < 8; k++) {
        int idx = k * 256 + t;
        int pl = idx >> 5;
        int c = idx & 31;
        featT[((size_t)vb * HWW + base + pl) * CC + c] = tile[pl][c];
    }
}

// ---------------------------------------------------------------------------
// Kernel 2: fused warp+corr+softmax pipeline. Arithmetic BIT-FROZEN at r9.
// Perf change only: sequential 32-lane sums now go through LDS (1 ds_write +
// 8 ds_read_b128 + the same 32 in-order adds) instead of 32 dynamic-index
// shuffles (ds_bpermute) per loop. Values & order identical => identical bits.
// ---------------------------------------------------------------------------
__global__ __launch_bounds__(256) void main_kernel(const float* __restrict__ featT,
                                                   const float* __restrict__ wproj,
                                                   const float* __restrict__ depth_hypo,
                                                   const float* __restrict__ reg_w,
                                                   float* __restrict__ out) {
#pragma clang fp contract(off)
    __shared__ float s_ref[8][32];
    __shared__ float s_e[8][32];
    __shared__ float s_proj[4][12];
    __shared__ float s_regw[8];

    int t = threadIdx.x;
    int d = t & 31, pl = t >> 5;
    int base = t & 32;
    int pixbase = blockIdx.x * 8;
    int b = pixbase / HWW;
    int hwb = pixbase - b * HWW;

    s_ref[pl][d] = featT[((size_t)(b * HWW + hwb + pl)) * CC + d];
    if (t < 48) s_proj[t / 12][t % 12] = wproj[b * (VV - 1) * 12 + t];
    if (t < 8) s_regw[t] = reg_w[t];
    __syncthreads();

    int hw = hwb + pl;
    int y = hw >> 7, x = hw & (WW - 1);
    float fx = (float)x, fy = (float)y;
    float dep = depth_hypo[(size_t)(b * DD + d) * HWW + hw];

    float4 ref4[8];
#pragma unroll
    for (int g = 0; g < 8; g++) ref4[g] = *(const float4*)&s_ref[pl][g * 4];

    float accs[8];
#pragma unroll
    for (int g = 0; g < 8; g++) accs[g] = 0.f;
    float cws = 1e-8f;

    for (int vi = 0; vi < 4; vi++) {
        const float* pr = s_proj[vi];
        float rx = fmaf(pr[1], fy, pr[0] * fx) + pr[2];
        float ry = fmaf(pr[4], fy, pr[3] * fx) + pr[5];
        float rz = fmaf(pr[7], fy, pr[6] * fx) + pr[8];
        float X = rx * dep + pr[9];
        float Y = ry * dep + pr[10];
        float Z = rz * dep + pr[11];
        if (Z == 0.f) Z = 1e-9f;
        float px = X / Z, py = Y / Z;

        float x0f = floorf(px), y0f = floorf(py);
        float x1f = x0f + 1.0f, y1f = y0f + 1.0f;
        float wx1 = px - x0f, wx0 = 1.0f - wx1;
        float wy1 = py - y0f, wy0 = 1.0f - wy1;
        bool vx0 = (x0f >= 0.f) && (x0f <= (float)(WW - 1));
        bool vx1 = (x1f >= 0.f) && (x1f <= (float)(WW - 1));
        bool vy0 = (y0f >= 0.f) && (y0f <= (float)(HH - 1));
        bool vy1 = (y1f >= 0.f) && (y1f <= (float)(HH - 1));

        int xc0 = (int)fminf(fmaxf(x0f, 0.f), (float)(WW - 1));
        int xc1 = (int)fminf(fmaxf(x1f, 0.f), (float)(WW - 1));
        int yc0 = (int)fminf(fmaxf(y0f, 0.f), (float)(HH - 1));
        int yc1 = (int)fminf(fmaxf(y1f, 0.f), (float)(HH - 1));

        float w00 = (wx0 * wy0) * ((vx0 && vy0) ? 1.f : 0.f);
        float w10 = (wx1 * wy0) * ((vx1 && vy0) ? 1.f : 0.f);
        float w01 = (wx0 * wy1) * ((vx0 && vy1) ? 1.f : 0.f);
        float w11 = (wx1 * wy1) * ((vx1 && vy1) ? 1.f : 0.f);

        const float* srcB = featT + (size_t)((vi + 1) * BB + b) * HWW * CC;
        const float4* p00 = (const float4*)(srcB + ((size_t)yc0 * WW + xc0) * CC);
        const float4* p10 = (const float4*)(srcB + ((size_t)yc0 * WW + xc1) * CC);
        const float4* p01 = (const float4*)(srcB + ((size_t)yc1 * WW + xc0) * CC);
        const float4* p11 = (const float4*)(srcB + ((size_t)yc1 * WW + xc1) * CC);

        float cf[8];
        float s = 0.f;
#pragma unroll
        for (int g = 0; g < 8; g++) {
            float4 f00 = p00[g], f10 = p10[g], f01 = p01[g], f11 = p11[g];
            float wrp[4];
            {
                float a;
                a = f00.x * w00; a = a + f10.x * w10; a = a + f01.x * w01; a = a + f11.x * w11; wrp[0] = a;
                a = f00.y * w00; a = a + f10.y * w10; a = a + f01.y * w01; a = a + f11.y * w11; wrp[1] = a;
                a = f00.z * w00; a = a + f10.z * w10; a = a + f01.z * w01; a = a + f11.z * w11; wrp[2] = a;
                a = f00.w * w00; a = a + f10.w * w10; a = a + f01.w * w01; a = a + f11.w * w11; wrp[3] = a;
            }
            float pr0 = wrp[0] * ref4[g].x;
            float pr1 = wrp[1] * ref4[g].y;
            float pr2 = wrp[2] * ref4[g].z;
            float pr3 = wrp[3] * ref4[g].w;
            float gs = pr0;
            gs = gs + pr1; gs = gs + pr2; gs = gs + pr3;
            gs = gs * 0.25f;
            cf[g] = gs;
            s = s + gs;
        }

        // softmax over d: max butterfly (order-free), denominator via LDS
        // round-trip + the SAME sequential d-order adds (bit-identical).
        float m = s;
#pragma unroll
        for (int msk = 1; msk < 32; msk <<= 1) m = fmaxf(m, __shfl_xor(m, msk, 64));
        float e = expf(s - m);
        s_e[pl][d] = e;
        float sum = 0.f;
#pragma unroll
        for (int j = 0; j < 8; j++) {
            float4 q = *(const float4*)&s_e[pl][j * 4];
            sum = sum + q.x; sum = sum + q.y; sum = sum + q.z; sum = sum + q.w;
        }
        float cw = (e / sum) * 0.17677669529663687f;

        cws = cws + cw;
#pragma unroll
        for (int g = 0; g < 8; g++) {
            float tterm = cw * cf[g];
            accs[g] = accs[g] + tterm;
        }
    }

    // logit: elementwise /cws then einsum FMA chain over g
    float logit = 0.f;
#pragma unroll
    for (int g = 0; g < 8; g++) {
        float cfn = accs[g] / cws;
        logit = fmaf(s_regw[g], cfn, logit);
    }

    // final softmax over d (same LDS pattern)
    float m2 = logit;
#pragma unroll
    for (int msk = 1; msk < 32; msk <<= 1) m2 = fmaxf(m2, __shfl_xor(m2, msk, 64));
    float e2 = expf(logit - m2);
    s_e[pl][d] = e2;
    float s2 = 0.f;
#pragma unroll
    for (int j = 0; j < 8; j++) {
        float4 q = *(const float4*)&s_e[pl][j * 4];
        s2 = s2 + q.x; s2 = s2 + q.y; s2 = s2 + q.z; s2 = s2 + q.w;
    }
    float attn = e2 / s2;
    out[(size_t)BB * HWW + (size_t)(b * DD + d) * HWW + hw] = attn;

    // np.argmax: bitwise max (butterfly) + min lane holding it
    float a1 = attn;
#pragma unroll
    for (int msk = 1; msk < 32; msk <<= 1) a1 = fmaxf(a1, __shfl_xor(a1, msk, 64));
    int idx1 = (attn == a1) ? d : 1000;
#pragma unroll
    for (int msk = 1; msk < 32; msk <<= 1) {
        int oi = __shfl_xor(idx1, msk, 64);
        idx1 = (oi < idx1) ? oi : idx1;
    }
    float dep1 = __shfl(dep, base + idx1, 64);
    if (d == 0) out[b * HWW + hw] = dep1;
}

// ---------------------------------------------------------------------------
extern "C" void kernel_launch(void* const* d_in, const int* in_sizes, int n_in,
                              void* d_out, int out_size, void* d_ws, size_t ws_size,
                              hipStream_t stream) {
    const float* features   = (const float*)d_in[0];   // [V,B,C,H,W]
    const float* pm         = (const float*)d_in[1];   // [B,V,2,4,4]
    const float* depth_hypo = (const float*)d_in[2];   // [B,D,H,W]
    const float* reg_w      = (const float*)d_in[3];   // [G]
    float* out = (float*)d_out;                        // depth [B,H,W] ++ attn [B,D,H,W]

    float* wproj = (float*)d_ws;                       // 96 floats
    float* featT = (float*)((char*)d_ws + 4096);       // [VB,H,W,C] = 21 MB

    prep_kernel<<<TRBLOCKS + 1, 256, 0, stream>>>(features, featT, pm, wproj);
    main_kernel<<<BB * HWW / 8, 256, 0, stream>>>(featT, wproj, depth_hypo, reg_w, out);
}